// Round 7
// baseline (231.014 us; speedup 1.0000x reference)
//
#include <hip/hip_runtime.h>
#include <hip/hip_bf16.h>
#include <stdint.h>

typedef __bf16 bf16_t;
typedef __attribute__((ext_vector_type(8))) __bf16 bf16x8;
typedef __attribute__((ext_vector_type(4))) __bf16 bf16x4;
typedef __attribute__((ext_vector_type(4))) float f32x4;

static constexpr int T_SEQ = 2048;
static constexpr int HID   = 2048;
static constexpr int NHEAD = 32;
static constexpr int NKVH  = 8;
static constexpr int HDIM  = 64;
static constexpr int QKVD  = 3072;   // 64*(32+16)

__device__ inline f32x4 mfma16(bf16x8 a, bf16x8 b, f32x4 c) {
    return __builtin_amdgcn_mfma_f32_16x16x32_bf16(a, b, c, 0, 0, 0);
}

__device__ inline void load_lds16(const bf16_t* g, bf16_t* l) {
    __builtin_amdgcn_global_load_lds(
        (const __attribute__((address_space(1))) void*)g,
        (__attribute__((address_space(3))) void*)l, 16, 0, 0);
}

// ---------------- prep: weight transposes + RMSNorm (one dispatch) ----------------
// blocks [0,1536): Wq transpose; [1536,2560): Wo transpose; [2560,4608): rmsnorm rows.
__global__ __launch_bounds__(256) void prep_kernel(const float* __restrict__ Wq,
                                                   const float* __restrict__ Wo,
                                                   bf16_t* __restrict__ Tq,
                                                   bf16_t* __restrict__ To,
                                                   const float* __restrict__ x,
                                                   const float* __restrict__ scale,
                                                   bf16_t* __restrict__ normed) {
    __shared__ float tile[64 * 65];
    int b = blockIdx.x;
    const int t = threadIdx.x;
    if (b < 2560) {
        const float* in; bf16_t* outw; int NN, KK, bx, by;
        if (b < 1536) { in = Wq; outw = Tq; NN = QKVD; KK = HID; bx = b % 48; by = b / 48; }
        else { b -= 1536; in = Wo; outw = To; NN = HID; KK = HID; bx = b % 32; by = b / 32; }
        const int c4 = (t & 15) * 4;
#pragma unroll
        for (int i = 0; i < 4; ++i) {
            int r = (t >> 4) + i * 16;
            float4 v = *(const float4*)(in + (size_t)(by*64 + r) * NN + bx*64 + c4);
            tile[r*65 + c4 + 0] = v.x; tile[r*65 + c4 + 1] = v.y;
            tile[r*65 + c4 + 2] = v.z; tile[r*65 + c4 + 3] = v.w;
        }
        __syncthreads();
        const int kc = t & 7;
#pragma unroll
        for (int i = 0; i < 2; ++i) {
            int n = (t >> 3) + i * 32;
            bf16x8 o;
#pragma unroll
            for (int j = 0; j < 8; ++j) o[j] = (bf16_t)tile[(kc*8 + j)*65 + n];
            *(bf16x8*)(outw + (size_t)(bx*64 + n) * KK + by*64 + kc*8) = o;
        }
    } else {
        int row = b - 2560;
        const float4* x4 = (const float4*)(x + (size_t)row * HID);
        const float4* s4 = (const float4*)scale;
        float4 v0 = x4[t], v1 = x4[t + 256];
        float ss = v0.x*v0.x + v0.y*v0.y + v0.z*v0.z + v0.w*v0.w
                 + v1.x*v1.x + v1.y*v1.y + v1.z*v1.z + v1.w*v1.w;
#pragma unroll
        for (int off = 32; off > 0; off >>= 1) ss += __shfl_down(ss, off);
        if ((t & 63) == 0) tile[t >> 6] = ss;
        __syncthreads();
        float total = tile[0] + tile[1] + tile[2] + tile[3];
        float inv = rsqrtf(total * (1.0f / HID) + 1e-5f);
        float4 sc0 = s4[t], sc1 = s4[t + 256];
        bf16_t* outr = normed + (size_t)row * HID;
        bf16x4 o0, o1;
        o0.x = (bf16_t)(v0.x*inv*sc0.x); o0.y = (bf16_t)(v0.y*inv*sc0.y);
        o0.z = (bf16_t)(v0.z*inv*sc0.z); o0.w = (bf16_t)(v0.w*inv*sc0.w);
        o1.x = (bf16_t)(v1.x*inv*sc1.x); o1.y = (bf16_t)(v1.y*inv*sc1.y);
        o1.z = (bf16_t)(v1.z*inv*sc1.z); o1.w = (bf16_t)(v1.w*inv*sc1.w);
        *(bf16x4*)(outr + 4*t)        = o0;
        *(bf16x4*)(outr + 1024 + 4*t) = o1;
    }
}

// ======== 32x128 full-K GEMM core (shared by the two fused kernels) ========
// Tile BM=32 x BN=128, full K per block -> grid (N/128, M/32): 1536 blocks (QKV, 6/CU) /
// 1024 blocks (out, 4/CU). Latency-bound diagnosis (r6): all pipes idle at 3 blocks/CU;
// this doubles resident blocks for TLP. Wave w owns rows (w>>1)*16..+16, cols (w&1)*64..+64,
// acc[1][4] -> rope col/col+32 pairing stays in-wave (j -> j+2).
// Verified staging/swizzle geometry: chunk cid -> global (r=cid>>2, c=(cid&3)^((r>>1)&3));
// frag read offset (quad^((lm>>1)&3))*8. A-tile: waves 0-1 stage ks=0 half, waves 2-3 ks=1
// (wave-uniform LDS base wave*512; +32 k-offset is wave-uniform).
#define GEMM32_CORE(Aptr, Btptr, Kdim)                                          \
    __shared__ __align__(16) bf16_t Asm[2 * 32 * 32];   /* 4 KB */              \
    __shared__ __align__(16) bf16_t Bsm[2 * 128 * 32];  /* 16 KB */             \
    const int K = (Kdim);                                                       \
    const int tid = threadIdx.x;                                                \
    const int bm = blockIdx.y * 32, bn = blockIdx.x * 128;                      \
    const int lane = tid & 63, wave = tid >> 6;                                 \
    const int wm = (wave >> 1) * 16, wn = (wave & 1) * 64;                      \
    const int lm = lane & 15, quad = lane >> 4;                                 \
    f32x4 acc[4];                                                               \
    _Pragma("unroll")                                                           \
    for (int j = 0; j < 4; ++j) acc[j] = (f32x4){0.f, 0.f, 0.f, 0.f};           \
    const int acid = tid & 127;                                                 \
    const int ar = acid >> 2, ac = (acid & 3) ^ ((ar >> 1) & 3);                \
    const int aks = (tid >= 128) ? 32 : 0;   /* wave-uniform */                 \
    const int r0 = tid >> 2, c0 = (tid & 3) ^ ((r0 >> 1) & 3);                  \
    const int cid1 = tid + 256;                                                 \
    const int r1 = cid1 >> 2, c1 = (cid1 & 3) ^ ((r1 >> 1) & 3);                \
    const bf16_t* Ab = (Aptr) + (size_t)bm * K;                                 \
    const bf16_t* Bb = (Btptr) + (size_t)bn * K;                                \
    const size_t gaA  = (size_t)ar * K + ac * 8 + aks;                          \
    const size_t gaB0 = (size_t)r0 * K + c0 * 8;                                \
    const size_t gaB1 = (size_t)r1 * K + c1 * 8;                                \
    bf16_t* ldsA   = &Asm[wave * 512];                                          \
    bf16_t* ldsB0a = &Bsm[wave * 512];                                          \
    bf16_t* ldsB0b = &Bsm[2048 + wave * 512];                                   \
    bf16_t* ldsB1a = &Bsm[4096 + wave * 512];                                   \
    bf16_t* ldsB1b = &Bsm[4096 + 2048 + wave * 512];                            \
    const int swz = (quad ^ ((lm >> 1) & 3)) * 8;                               \
    for (int k0 = 0; k0 < K; k0 += 64) {                                        \
        load_lds16(Ab + gaA  + k0,      ldsA);                                  \
        load_lds16(Bb + gaB0 + k0,      ldsB0a);                                \
        load_lds16(Bb + gaB1 + k0,      ldsB0b);                                \
        load_lds16(Bb + gaB0 + k0 + 32, ldsB1a);                                \
        load_lds16(Bb + gaB1 + k0 + 32, ldsB1b);                                \
        __syncthreads();                                                        \
        _Pragma("unroll")                                                       \
        for (int ks = 0; ks < 2; ++ks) {                                        \
            bf16x8 af, bfr[4];                                                  \
            af = *(const bf16x8*)&Asm[ks*1024 + (wm + lm)*32 + swz];            \
            _Pragma("unroll")                                                   \
            for (int j = 0; j < 4; ++j)                                         \
                bfr[j] = *(const bf16x8*)&Bsm[ks*4096 + (wn + j*16 + lm)*32 + swz]; \
            _Pragma("unroll")                                                   \
            for (int j = 0; j < 4; ++j) acc[j] = mfma16(af, bfr[j], acc[j]);    \
        }                                                                       \
        __syncthreads();                                                        \
    }

// ---------------- QKV GEMM with fused bias+RoPE+scatter epilogue --------------------
// grid (24, 64) = 1536 blocks = 6/CU. Epilogue holds final values (full K).
// Thread owns cols gc=bn+wn+j*16+lm; rope partner col+32 = j+2 (same lane/reg).
__global__ __launch_bounds__(256, 6) void gemm_qkv_rope(const bf16_t* __restrict__ A,
                                                        const bf16_t* __restrict__ Bt,
                                                        const float* __restrict__ qkvb,
                                                        const float* __restrict__ cost,
                                                        const float* __restrict__ sint,
                                                        bf16_t* __restrict__ Qb,
                                                        bf16_t* __restrict__ Kb,
                                                        bf16_t* __restrict__ Vb) {
    GEMM32_CORE(A, Bt, HID)

    const int gcb = bn + wn;                 // column base for this wave (mult of 64)
    bf16_t* dstbase; int cstride, coff; bool dorope;
    if (bn < 2048)      { dstbase = Qb; cstride = 2048; coff = 0;    dorope = true;  }
    else if (bn < 2560) { dstbase = Kb; cstride = 512;  coff = 2048; dorope = true;  }
    else                { dstbase = Vb; cstride = 512;  coff = 2560; dorope = false; }
    float bj[4];
#pragma unroll
    for (int j = 0; j < 4; ++j) bj[j] = qkvb[gcb + j*16 + lm];
    const int colb = gcb - coff + lm;

    const int tr = bm + wm + quad*4;
#pragma unroll
    for (int r = 0; r < 4; ++r) {
        const int t = tr + r;
        bf16_t* drow = dstbase + (size_t)t * cstride + colb;
        if (dorope) {
            float c0 = cost[t*32 + lm],      s0 = sint[t*32 + lm];
            float c1 = cost[t*32 + 16 + lm], s1 = sint[t*32 + 16 + lm];
            float x10 = acc[0][r] + bj[0], x20 = acc[2][r] + bj[2];
            float x11 = acc[1][r] + bj[1], x21 = acc[3][r] + bj[3];
            drow[0]  = (bf16_t)(x10*c0 - x20*s0);
            drow[16] = (bf16_t)(x11*c1 - x21*s1);
            drow[32] = (bf16_t)(x20*c0 + x10*s0);
            drow[48] = (bf16_t)(x21*c1 + x11*s1);
        } else {
            drow[0]  = (bf16_t)(acc[0][r] + bj[0]);
            drow[16] = (bf16_t)(acc[1][r] + bj[1]);
            drow[32] = (bf16_t)(acc[2][r] + bj[2]);
            drow[48] = (bf16_t)(acc[3][r] + bj[3]);
        }
    }
}

// ---------------- out-proj GEMM with fused bias+residual epilogue (fp32 out) --------
// grid (16, 64) = 1024 blocks = 4/CU. Replaces split-K out GEMM + combine_out.
__global__ __launch_bounds__(256, 6) void gemm_out_res(const bf16_t* __restrict__ A,
                                                       const bf16_t* __restrict__ Bt,
                                                       const float* __restrict__ bias,
                                                       const float* __restrict__ x,
                                                       float* __restrict__ out) {
    GEMM32_CORE(A, Bt, HID)

    const int gcb = bn + wn;
    float bj[4];
#pragma unroll
    for (int j = 0; j < 4; ++j) bj[j] = bias[gcb + j*16 + lm];

    const int tr = bm + wm + quad*4;
#pragma unroll
    for (int r = 0; r < 4; ++r) {
        const int t = tr + r;
        const float* xrow = x + (size_t)t * HID;
        float* orow = out + (size_t)t * HID;
#pragma unroll
        for (int j = 0; j < 4; ++j) {
            const int gc = gcb + j*16 + lm;
            orow[gc] = acc[j][r] + bj[j] + xrow[gc];
        }
    }
}

// ---------------- attention: direct global Q/K frags, one barrier, conflict-free Vt ------
__global__ __launch_bounds__(256) void attn_kernel(const bf16_t* __restrict__ Qb,
                                                   const bf16_t* __restrict__ Kb,
                                                   const bf16_t* __restrict__ Vb,
                                                   const float* __restrict__ sinks,
                                                   bf16_t* __restrict__ attnb) {
    __shared__ __align__(16) bf16_t Vt[64 * 200];
    __shared__ __align__(16) bf16_t Ws[64 * 200];

    const int tid = threadIdx.x;
    const int qt = blockIdx.x, h = blockIdx.y;
    const int qs = qt * 64;
    const int nkv = h >> 2;

    // V^T staging, conflict-free: lanes 0..31 of each half write 32 consecutive words.
    {
        const int off = (tid >> 5) * 8;
#pragma unroll
        for (int it = 0; it < 3; ++it) {
            int j2 = (tid & 31) + 32 * it;
            int kg0 = qs - 128 + 2*j2;     if (kg0 < 0) kg0 = 0;
            int kg1 = qs - 128 + 2*j2 + 1; if (kg1 < 0) kg1 = 0;
            union { uint4 u; bf16_t e[8]; } v0, v1;
            v0.u = *(const uint4*)(Vb + ((size_t)kg0*NKVH + nkv)*HDIM + off);
            v1.u = *(const uint4*)(Vb + ((size_t)kg1*NKVH + nkv)*HDIM + off);
#pragma unroll
            for (int r = 0; r < 8; ++r) {
                union { uint u; bf16_t e[2]; } p;
                p.e[0] = v0.e[r]; p.e[1] = v1.e[r];
                *(uint*)&Vt[(off + r)*200 + 2*j2] = p.u;
            }
        }
    }

    const int lane = tid & 63, wave = tid >> 6;
    const int lm = lane & 15, quad = lane >> 4;
    const int w16 = wave * 16;

    f32x4 S[12];
#pragma unroll
    for (int jt = 0; jt < 12; ++jt) S[jt] = (f32x4){0.f, 0.f, 0.f, 0.f};
    const bf16_t* Qrow = Qb + ((size_t)(qs + w16 + lm)*NHEAD + h)*HDIM + quad*8;
    int krow[12];
#pragma unroll
    for (int jt = 0; jt < 12; ++jt) {
        int kg = qs - 128 + jt*16 + lm;
        krow[jt] = kg < 0 ? 0 : kg;
    }
    __builtin_amdgcn_s_setprio(1);
#pragma unroll
    for (int ks = 0; ks < 2; ++ks) {
        bf16x8 aq = *(const bf16x8*)(Qrow + ks*32);
#pragma unroll
        for (int jt = 0; jt < 12; ++jt) {
            bf16x8 bk = *(const bf16x8*)(Kb + ((size_t)krow[jt]*NKVH + nkv)*HDIM + ks*32 + quad*8);
            S[jt] = mfma16(aq, bk, S[jt]);
        }
    }
    __builtin_amdgcn_s_setprio(0);

    const float sink = sinks[h];
#pragma unroll
    for (int reg = 0; reg < 4; ++reg) {
        const int qg = qs + w16 + quad*4 + reg;
        float mx = -1e30f;
#pragma unroll
        for (int jt = 0; jt < 12; ++jt) {
            int kg = qs - 128 + jt*16 + lm;
            float sv = S[jt][reg] * 0.125f;
            bool valid = (kg >= 0) && (kg <= qg) && (qg - kg <= 128);
            sv = valid ? sv : -1e30f;
            S[jt][reg] = sv;
            mx = fmaxf(mx, sv);
        }
#pragma unroll
        for (int off = 1; off < 16; off <<= 1) mx = fmaxf(mx, __shfl_xor(mx, off));
        float M = fmaxf(mx, sink);
        float sum = 0.f;
#pragma unroll
        for (int jt = 0; jt < 12; ++jt) {
            float e = __expf(S[jt][reg] - M);
            S[jt][reg] = e; sum += e;
        }
#pragma unroll
        for (int off = 1; off < 16; off <<= 1) sum += __shfl_xor(sum, off);
        float rden = 1.f / (sum + __expf(sink - M));
#pragma unroll
        for (int jt = 0; jt < 12; ++jt)
            Ws[(w16 + quad*4 + reg)*200 + jt*16 + lm] = (bf16_t)(S[jt][reg] * rden);
    }
    __syncthreads();

    f32x4 O[4];
#pragma unroll
    for (int nt = 0; nt < 4; ++nt) O[nt] = (f32x4){0.f, 0.f, 0.f, 0.f};
    __builtin_amdgcn_s_setprio(1);
#pragma unroll
    for (int ks = 0; ks < 6; ++ks) {
        bf16x8 aw = *(const bf16x8*)&Ws[(w16 + lm)*200 + ks*32 + quad*8];
#pragma unroll
        for (int nt = 0; nt < 4; ++nt) {
            bf16x8 bv = *(const bf16x8*)&Vt[(nt*16 + lm)*200 + ks*32 + quad*8];
            O[nt] = mfma16(aw, bv, O[nt]);
        }
    }
    __builtin_amdgcn_s_setprio(0);
#pragma unroll
    for (int nt = 0; nt < 4; ++nt)
#pragma unroll
        for (int reg = 0; reg < 4; ++reg)
            attnb[(size_t)(qs + w16 + quad*4 + reg)*HID + h*HDIM + nt*16 + lm] =
                (bf16_t)(O[nt][reg]);
}

// ---------------- launch ----------------
extern "C" void kernel_launch(void* const* d_in, const int* in_sizes, int n_in,
                              void* d_out, int out_size, void* d_ws, size_t ws_size,
                              hipStream_t stream) {
    (void)in_sizes; (void)n_in; (void)out_size; (void)ws_size;
    const float* x          = (const float*)d_in[0];
    const float* scale      = (const float*)d_in[1];
    const float* sinks      = (const float*)d_in[2];
    const float* qkv_kernel = (const float*)d_in[3];
    const float* qkv_bias   = (const float*)d_in[4];
    const float* out_kernel = (const float*)d_in[5];
    const float* out_bias   = (const float*)d_in[6];
    const float* cos_t      = (const float*)d_in[7];
    const float* sin_t      = (const float*)d_in[8];
    float* out = (float*)d_out;

    // ws plan (64 MiB, aliasing by liveness):
    //   [ 0, 8)   Wt_out  bf16 [2048][2048]  (alive all run)
    //   [ 8,20)   Wt_qkv  bf16 [3072][2048]  (dead after QKV gemm)
    //   [ 8,16)   attnb   bf16 [T][2048]     (aliases Wt_qkv; written by attn)
    //   [20,28)   normed  bf16 [T][2048]
    //   [28,36)   Qb      bf16 [T][2048]
    //   [36,38)   Kb      bf16 [T][512]
    //   [38,40)   Vb      bf16 [T][512]
    char* ws = (char*)d_ws;
    const size_t MiB = 1048576;
    bf16_t* Wt_out = (bf16_t*)(ws);
    bf16_t* Wt_qkv = (bf16_t*)(ws + 8*MiB);
    bf16_t* attnb  = (bf16_t*)(ws + 8*MiB);
    bf16_t* normed = (bf16_t*)(ws + 20*MiB);
    bf16_t* Qb     = (bf16_t*)(ws + 28*MiB);
    bf16_t* Kb     = (bf16_t*)(ws + 36*MiB);
    bf16_t* Vb     = (bf16_t*)(ws + 38*MiB);

    prep_kernel<<<4608, 256, 0, stream>>>(qkv_kernel, out_kernel, Wt_qkv, Wt_out,
                                          x, scale, normed);
    gemm_qkv_rope<<<dim3(QKVD/128, T_SEQ/32), 256, 0, stream>>>(normed, Wt_qkv,
                                                                qkv_bias, cos_t, sin_t,
                                                                Qb, Kb, Vb);
    attn_kernel<<<dim3(T_SEQ/64, NHEAD), 256, 0, stream>>>(Qb, Kb, Vb, sinks, attnb);
    gemm_out_res<<<dim3(HID/128, T_SEQ/32), 256, 0, stream>>>(attnb, Wt_out,
                                                              out_bias, x, out);
}

// Round 8
// 201.667 us; speedup vs baseline: 1.1455x; 1.1455x over previous
//
#include <hip/hip_runtime.h>
#include <hip/hip_bf16.h>
#include <stdint.h>

typedef __bf16 bf16_t;
typedef __attribute__((ext_vector_type(8))) __bf16 bf16x8;
typedef __attribute__((ext_vector_type(4))) __bf16 bf16x4;
typedef __attribute__((ext_vector_type(4))) float f32x4;

static constexpr int T_SEQ = 2048;
static constexpr int HID   = 2048;
static constexpr int NHEAD = 32;
static constexpr int NKVH  = 8;
static constexpr int HDIM  = 64;
static constexpr int QKVD  = 3072;   // 64*(32+16)

__device__ inline f32x4 mfma16(bf16x8 a, bf16x8 b, f32x4 c) {
    return __builtin_amdgcn_mfma_f32_16x16x32_bf16(a, b, c, 0, 0, 0);
}

__device__ inline void load_lds16(const bf16_t* g, bf16_t* l) {
    __builtin_amdgcn_global_load_lds(
        (const __attribute__((address_space(1))) void*)g,
        (__attribute__((address_space(3))) void*)l, 16, 0, 0);
}

// ---------------- prep: weight transposes + RMSNorm (one dispatch) ----------------
// blocks [0,1536): Wq transpose; [1536,2560): Wo transpose; [2560,4608): rmsnorm rows.
__global__ __launch_bounds__(256) void prep_kernel(const float* __restrict__ Wq,
                                                   const float* __restrict__ Wo,
                                                   bf16_t* __restrict__ Tq,
                                                   bf16_t* __restrict__ To,
                                                   const float* __restrict__ x,
                                                   const float* __restrict__ scale,
                                                   bf16_t* __restrict__ normed) {
    __shared__ float tile[64 * 65];
    int b = blockIdx.x;
    const int t = threadIdx.x;
    if (b < 2560) {
        const float* in; bf16_t* outw; int NN, KK, bx, by;
        if (b < 1536) { in = Wq; outw = Tq; NN = QKVD; KK = HID; bx = b % 48; by = b / 48; }
        else { b -= 1536; in = Wo; outw = To; NN = HID; KK = HID; bx = b % 32; by = b / 32; }
        const int c4 = (t & 15) * 4;
#pragma unroll
        for (int i = 0; i < 4; ++i) {
            int r = (t >> 4) + i * 16;
            float4 v = *(const float4*)(in + (size_t)(by*64 + r) * NN + bx*64 + c4);
            tile[r*65 + c4 + 0] = v.x; tile[r*65 + c4 + 1] = v.y;
            tile[r*65 + c4 + 2] = v.z; tile[r*65 + c4 + 3] = v.w;
        }
        __syncthreads();
        const int kc = t & 7;
#pragma unroll
        for (int i = 0; i < 2; ++i) {
            int n = (t >> 3) + i * 32;
            bf16x8 o;
#pragma unroll
            for (int j = 0; j < 8; ++j) o[j] = (bf16_t)tile[(kc*8 + j)*65 + n];
            *(bf16x8*)(outw + (size_t)(bx*64 + n) * KK + by*64 + kc*8) = o;
        }
    } else {
        int row = b - 2560;
        const float4* x4 = (const float4*)(x + (size_t)row * HID);
        const float4* s4 = (const float4*)scale;
        float4 v0 = x4[t], v1 = x4[t + 256];
        float ss = v0.x*v0.x + v0.y*v0.y + v0.z*v0.z + v0.w*v0.w
                 + v1.x*v1.x + v1.y*v1.y + v1.z*v1.z + v1.w*v1.w;
#pragma unroll
        for (int off = 32; off > 0; off >>= 1) ss += __shfl_down(ss, off);
        if ((t & 63) == 0) tile[t >> 6] = ss;
        __syncthreads();
        float total = tile[0] + tile[1] + tile[2] + tile[3];
        float inv = rsqrtf(total * (1.0f / HID) + 1e-5f);
        float4 sc0 = s4[t], sc1 = s4[t + 256];
        bf16_t* outr = normed + (size_t)row * HID;
        bf16x4 o0, o1;
        o0.x = (bf16_t)(v0.x*inv*sc0.x); o0.y = (bf16_t)(v0.y*inv*sc0.y);
        o0.z = (bf16_t)(v0.z*inv*sc0.z); o0.w = (bf16_t)(v0.w*inv*sc0.w);
        o1.x = (bf16_t)(v1.x*inv*sc1.x); o1.y = (bf16_t)(v1.y*inv*sc1.y);
        o1.z = (bf16_t)(v1.z*inv*sc1.z); o1.w = (bf16_t)(v1.w*inv*sc1.w);
        *(bf16x4*)(outr + 4*t)        = o0;
        *(bf16x4*)(outr + 1024 + 4*t) = o1;
    }
}

// ======== 64x128 full-K GEMM core (round-6 verified: 205.8 us total) ========
// Tile BM=64 x BN=128, full K per block -> grid (N/128, M/64): 768 blocks (QKV, 3/CU) /
// 512 blocks (out, 2/CU). r7 falsified smaller tiles (BM=32: 2x B-staging traffic through
// L2 -> 59us). 2-phase structure at its measured ceiling (~638 TF on this shape).
#define GEMM64_CORE(Aptr, Btptr, Kdim)                                          \
    __shared__ __align__(16) bf16_t Asm[2 * 64 * 32];   /* 8 KB */              \
    __shared__ __align__(16) bf16_t Bsm[2 * 128 * 32];  /* 16 KB */             \
    const int K = (Kdim);                                                       \
    const int tid = threadIdx.x;                                                \
    const int bm = blockIdx.y * 64, bn = blockIdx.x * 128;                      \
    const int lane = tid & 63, wave = tid >> 6;                                 \
    const int wm = (wave & 1) * 32, wn = (wave >> 1) * 64;                      \
    const int lm = lane & 15, quad = lane >> 4;                                 \
    f32x4 acc[2][4];                                                            \
    _Pragma("unroll")                                                           \
    for (int i = 0; i < 2; ++i)                                                 \
        _Pragma("unroll")                                                       \
        for (int j = 0; j < 4; ++j) acc[i][j] = (f32x4){0.f, 0.f, 0.f, 0.f};    \
    const int r0 = tid >> 2, c0 = (tid & 3) ^ ((r0 >> 1) & 3);                  \
    const int cid1 = tid + 256;                                                 \
    const int r1 = cid1 >> 2, c1 = (cid1 & 3) ^ ((r1 >> 1) & 3);                \
    const bf16_t* Ab = (Aptr) + (size_t)bm * K;                                 \
    const bf16_t* Bb = (Btptr) + (size_t)bn * K;                                \
    const size_t gaA  = (size_t)r0 * K + c0 * 8;                                \
    const size_t gaB0 = (size_t)r0 * K + c0 * 8;                                \
    const size_t gaB1 = (size_t)r1 * K + c1 * 8;                                \
    bf16_t* ldsA0  = &Asm[wave * 512];                                          \
    bf16_t* ldsA1  = &Asm[2048 + wave * 512];                                   \
    bf16_t* ldsB0a = &Bsm[wave * 512];                                          \
    bf16_t* ldsB0b = &Bsm[2048 + wave * 512];                                   \
    bf16_t* ldsB1a = &Bsm[4096 + wave * 512];                                   \
    bf16_t* ldsB1b = &Bsm[4096 + 2048 + wave * 512];                            \
    const int swz = (quad ^ ((lm >> 1) & 3)) * 8;                               \
    for (int k0 = 0; k0 < K; k0 += 64) {                                        \
        load_lds16(Ab + gaA  + k0,      ldsA0);                                 \
        load_lds16(Ab + gaA  + k0 + 32, ldsA1);                                 \
        load_lds16(Bb + gaB0 + k0,      ldsB0a);                                \
        load_lds16(Bb + gaB1 + k0,      ldsB0b);                                \
        load_lds16(Bb + gaB0 + k0 + 32, ldsB1a);                                \
        load_lds16(Bb + gaB1 + k0 + 32, ldsB1b);                                \
        __syncthreads();                                                        \
        _Pragma("unroll")                                                       \
        for (int ks = 0; ks < 2; ++ks) {                                        \
            bf16x8 af[2], bfr[4];                                               \
            _Pragma("unroll")                                                   \
            for (int i = 0; i < 2; ++i)                                         \
                af[i]  = *(const bf16x8*)&Asm[ks*2048 + (wm + i*16 + lm)*32 + swz]; \
            _Pragma("unroll")                                                   \
            for (int j = 0; j < 4; ++j)                                         \
                bfr[j] = *(const bf16x8*)&Bsm[ks*4096 + (wn + j*16 + lm)*32 + swz]; \
            _Pragma("unroll")                                                   \
            for (int i = 0; i < 2; ++i)                                         \
                _Pragma("unroll")                                               \
                for (int j = 0; j < 4; ++j) acc[i][j] = mfma16(af[i], bfr[j], acc[i][j]); \
        }                                                                       \
        __syncthreads();                                                        \
    }

// ---------------- QKV GEMM with fused bias+RoPE+scatter epilogue --------------------
__global__ __launch_bounds__(256) void gemm_qkv_rope(const bf16_t* __restrict__ A,
                                                     const bf16_t* __restrict__ Bt,
                                                     const float* __restrict__ qkvb,
                                                     const float* __restrict__ cost,
                                                     const float* __restrict__ sint,
                                                     bf16_t* __restrict__ Qb,
                                                     bf16_t* __restrict__ Kb,
                                                     bf16_t* __restrict__ Vb) {
    GEMM64_CORE(A, Bt, HID)

    const int gcb = bn + wn;                 // column base for this wave (mult of 64)
    bf16_t* dstbase; int cstride, coff; bool dorope;
    if (bn < 2048)      { dstbase = Qb; cstride = 2048; coff = 0;    dorope = true;  }
    else if (bn < 2560) { dstbase = Kb; cstride = 512;  coff = 2048; dorope = true;  }
    else                { dstbase = Vb; cstride = 512;  coff = 2560; dorope = false; }
    float bj[4];
#pragma unroll
    for (int j = 0; j < 4; ++j) bj[j] = qkvb[gcb + j*16 + lm];
    const int colb = gcb - coff + lm;

#pragma unroll
    for (int i = 0; i < 2; ++i) {
        const int tr = bm + wm + i*16 + quad*4;
#pragma unroll
        for (int r = 0; r < 4; ++r) {
            const int t = tr + r;
            bf16_t* drow = dstbase + (size_t)t * cstride + colb;
            if (dorope) {
                float c0 = cost[t*32 + lm],      s0 = sint[t*32 + lm];
                float c1 = cost[t*32 + 16 + lm], s1 = sint[t*32 + 16 + lm];
                float x10 = acc[i][0][r] + bj[0], x20 = acc[i][2][r] + bj[2];
                float x11 = acc[i][1][r] + bj[1], x21 = acc[i][3][r] + bj[3];
                drow[0]  = (bf16_t)(x10*c0 - x20*s0);
                drow[16] = (bf16_t)(x11*c1 - x21*s1);
                drow[32] = (bf16_t)(x20*c0 + x10*s0);
                drow[48] = (bf16_t)(x21*c1 + x11*s1);
            } else {
                drow[0]  = (bf16_t)(acc[i][0][r] + bj[0]);
                drow[16] = (bf16_t)(acc[i][1][r] + bj[1]);
                drow[32] = (bf16_t)(acc[i][2][r] + bj[2]);
                drow[48] = (bf16_t)(acc[i][3][r] + bj[3]);
            }
        }
    }
}

// ---------------- out-proj GEMM with fused bias+residual epilogue (fp32 out) --------
__global__ __launch_bounds__(256) void gemm_out_res(const bf16_t* __restrict__ A,
                                                    const bf16_t* __restrict__ Bt,
                                                    const float* __restrict__ bias,
                                                    const float* __restrict__ x,
                                                    float* __restrict__ out) {
    GEMM64_CORE(A, Bt, HID)

    const int gcb = bn + wn;
    float bj[4];
#pragma unroll
    for (int j = 0; j < 4; ++j) bj[j] = bias[gcb + j*16 + lm];

#pragma unroll
    for (int i = 0; i < 2; ++i) {
        const int tr = bm + wm + i*16 + quad*4;
#pragma unroll
        for (int r = 0; r < 4; ++r) {
            const int t = tr + r;
            const float* xrow = x + (size_t)t * HID;
            float* orow = out + (size_t)t * HID;
#pragma unroll
            for (int j = 0; j < 4; ++j) {
                const int gc = gcb + j*16 + lm;
                orow[gc] = acc[i][j][r] + bj[j] + xrow[gc];
            }
        }
    }
}

// ---------------- attention: 2 heads/block (shared KV group) -----------------------
// Grid (T/64, NHEAD/2) = 512 blocks, 4 waves, LDS 51.2 KB -> 3 blocks/CU.
// Heads 2*by and 2*by+1 share nkv -> Vt staged ONCE per pair (halves staging work and
// block count vs r6). Head loop is sequential (#pragma unroll 1) keeping the verified
// per-wave structure and VGPR footprint; K re-read from L2 per head (cheap, r3 lesson).
__global__ __launch_bounds__(256) void attn_kernel(const bf16_t* __restrict__ Qb,
                                                   const bf16_t* __restrict__ Kb,
                                                   const bf16_t* __restrict__ Vb,
                                                   const float* __restrict__ sinks,
                                                   bf16_t* __restrict__ attnb) {
    __shared__ __align__(16) bf16_t Vt[64 * 200];
    __shared__ __align__(16) bf16_t Ws[64 * 200];

    const int tid = threadIdx.x;
    const int qt = blockIdx.x, h0 = blockIdx.y * 2;
    const int qs = qt * 64;
    const int nkv = h0 >> 2;

    // V^T staging, conflict-free: lanes 0..31 of each half write 32 consecutive words.
    {
        const int off = (tid >> 5) * 8;
#pragma unroll
        for (int it = 0; it < 3; ++it) {
            int j2 = (tid & 31) + 32 * it;
            int kg0 = qs - 128 + 2*j2;     if (kg0 < 0) kg0 = 0;
            int kg1 = qs - 128 + 2*j2 + 1; if (kg1 < 0) kg1 = 0;
            union { uint4 u; bf16_t e[8]; } v0, v1;
            v0.u = *(const uint4*)(Vb + ((size_t)kg0*NKVH + nkv)*HDIM + off);
            v1.u = *(const uint4*)(Vb + ((size_t)kg1*NKVH + nkv)*HDIM + off);
#pragma unroll
            for (int r = 0; r < 8; ++r) {
                union { uint u; bf16_t e[2]; } p;
                p.e[0] = v0.e[r]; p.e[1] = v1.e[r];
                *(uint*)&Vt[(off + r)*200 + 2*j2] = p.u;
            }
        }
    }

    const int lane = tid & 63, wave = tid >> 6;
    const int lm = lane & 15, quad = lane >> 4;
    const int w16 = wave * 16;

    int krow[12];
#pragma unroll
    for (int jt = 0; jt < 12; ++jt) {
        int kg = qs - 128 + jt*16 + lm;
        krow[jt] = kg < 0 ? 0 : kg;
    }

#pragma unroll 1
    for (int hh = 0; hh < 2; ++hh) {
        const int h = h0 + hh;

        f32x4 S[12];
#pragma unroll
        for (int jt = 0; jt < 12; ++jt) S[jt] = (f32x4){0.f, 0.f, 0.f, 0.f};
        const bf16_t* Qrow = Qb + ((size_t)(qs + w16 + lm)*NHEAD + h)*HDIM + quad*8;
        __builtin_amdgcn_s_setprio(1);
#pragma unroll
        for (int ks = 0; ks < 2; ++ks) {
            bf16x8 aq = *(const bf16x8*)(Qrow + ks*32);
#pragma unroll
            for (int jt = 0; jt < 12; ++jt) {
                bf16x8 bk = *(const bf16x8*)(Kb + ((size_t)krow[jt]*NKVH + nkv)*HDIM + ks*32 + quad*8);
                S[jt] = mfma16(aq, bk, S[jt]);
            }
        }
        __builtin_amdgcn_s_setprio(0);

        const float sink = sinks[h];
#pragma unroll
        for (int reg = 0; reg < 4; ++reg) {
            const int qg = qs + w16 + quad*4 + reg;
            float mx = -1e30f;
#pragma unroll
            for (int jt = 0; jt < 12; ++jt) {
                int kg = qs - 128 + jt*16 + lm;
                float sv = S[jt][reg] * 0.125f;
                bool valid = (kg >= 0) && (kg <= qg) && (qg - kg <= 128);
                sv = valid ? sv : -1e30f;
                S[jt][reg] = sv;
                mx = fmaxf(mx, sv);
            }
#pragma unroll
            for (int off = 1; off < 16; off <<= 1) mx = fmaxf(mx, __shfl_xor(mx, off));
            float M = fmaxf(mx, sink);
            float sum = 0.f;
#pragma unroll
            for (int jt = 0; jt < 12; ++jt) {
                float e = __expf(S[jt][reg] - M);
                S[jt][reg] = e; sum += e;
            }
#pragma unroll
            for (int off = 1; off < 16; off <<= 1) sum += __shfl_xor(sum, off);
            float rden = 1.f / (sum + __expf(sink - M));
#pragma unroll
            for (int jt = 0; jt < 12; ++jt)
                Ws[(w16 + quad*4 + reg)*200 + jt*16 + lm] = (bf16_t)(S[jt][reg] * rden);
        }
        if (hh == 0) __syncthreads();   // Vt ready before first PV; Ws wave-private

        f32x4 O[4];
#pragma unroll
        for (int nt = 0; nt < 4; ++nt) O[nt] = (f32x4){0.f, 0.f, 0.f, 0.f};
        __builtin_amdgcn_s_setprio(1);
#pragma unroll
        for (int ks = 0; ks < 6; ++ks) {
            bf16x8 aw = *(const bf16x8*)&Ws[(w16 + lm)*200 + ks*32 + quad*8];
#pragma unroll
            for (int nt = 0; nt < 4; ++nt) {
                bf16x8 bv = *(const bf16x8*)&Vt[(nt*16 + lm)*200 + ks*32 + quad*8];
                O[nt] = mfma16(aw, bv, O[nt]);
            }
        }
        __builtin_amdgcn_s_setprio(0);
#pragma unroll
        for (int nt = 0; nt < 4; ++nt)
#pragma unroll
            for (int reg = 0; reg < 4; ++reg)
                attnb[(size_t)(qs + w16 + quad*4 + reg)*HID + h*HDIM + nt*16 + lm] =
                    (bf16_t)(O[nt][reg]);
    }
}

// ---------------- launch ----------------
extern "C" void kernel_launch(void* const* d_in, const int* in_sizes, int n_in,
                              void* d_out, int out_size, void* d_ws, size_t ws_size,
                              hipStream_t stream) {
    (void)in_sizes; (void)n_in; (void)out_size; (void)ws_size;
    const float* x          = (const float*)d_in[0];
    const float* scale      = (const float*)d_in[1];
    const float* sinks      = (const float*)d_in[2];
    const float* qkv_kernel = (const float*)d_in[3];
    const float* qkv_bias   = (const float*)d_in[4];
    const float* out_kernel = (const float*)d_in[5];
    const float* out_bias   = (const float*)d_in[6];
    const float* cos_t      = (const float*)d_in[7];
    const float* sin_t      = (const float*)d_in[8];
    float* out = (float*)d_out;

    // ws plan (64 MiB, aliasing by liveness):
    //   [ 0, 8)   Wt_out  bf16 [2048][2048]  (alive all run)
    //   [ 8,20)   Wt_qkv  bf16 [3072][2048]  (dead after QKV gemm)
    //   [ 8,16)   attnb   bf16 [T][2048]     (aliases Wt_qkv; written by attn)
    //   [20,28)   normed  bf16 [T][2048]
    //   [28,36)   Qb      bf16 [T][2048]
    //   [36,38)   Kb      bf16 [T][512]
    //   [38,40)   Vb      bf16 [T][512]
    char* ws = (char*)d_ws;
    const size_t MiB = 1048576;
    bf16_t* Wt_out = (bf16_t*)(ws);
    bf16_t* Wt_qkv = (bf16_t*)(ws + 8*MiB);
    bf16_t* attnb  = (bf16_t*)(ws + 8*MiB);
    bf16_t* normed = (bf16_t*)(ws + 20*MiB);
    bf16_t* Qb     = (bf16_t*)(ws + 28*MiB);
    bf16_t* Kb     = (bf16_t*)(ws + 36*MiB);
    bf16_t* Vb     = (bf16_t*)(ws + 38*MiB);

    prep_kernel<<<4608, 256, 0, stream>>>(qkv_kernel, out_kernel, Wt_qkv, Wt_out,
                                          x, scale, normed);
    gemm_qkv_rope<<<dim3(QKVD/128, T_SEQ/64), 256, 0, stream>>>(normed, Wt_qkv,
                                                                qkv_bias, cos_t, sin_t,
                                                                Qb, Kb, Vb);
    attn_kernel<<<dim3(T_SEQ/64, NHEAD/2), 256, 0, stream>>>(Qb, Kb, Vb, sinks, attnb);
    gemm_out_res<<<dim3(HID/128, T_SEQ/64), 256, 0, stream>>>(attnb, Wt_out,
                                                              out_bias, x, out);
}